// Round 3
// baseline (472.331 us; speedup 1.0000x reference)
//
#include <hip/hip_runtime.h>
#include <stdint.h>

#define DEV_INLINE __device__ __forceinline__

typedef __bf16 bf16x8 __attribute__((ext_vector_type(8)));
typedef float f32x4 __attribute__((ext_vector_type(4)));

typedef const __attribute__((address_space(1))) void* gas_ptr;
typedef __attribute__((address_space(3))) void* las_ptr;

DEV_INLINE unsigned short f2bf(float f) {
    union { float f; unsigned u; } v; v.f = f;
    unsigned r = v.u + 0x7fffu + ((v.u >> 16) & 1u);   // RNE
    return (unsigned short)(r >> 16);
}
DEV_INLINE float bf2f(unsigned short u) {
    union { unsigned u; float f; } v; v.u = ((unsigned)u) << 16;
    return v.f;
}

// ---------------- casts ----------------

__global__ void cast_bf16_kernel(const float* __restrict__ src,
                                 unsigned short* __restrict__ dst, long n4) {
    long i = (long)blockIdx.x * blockDim.x + threadIdx.x;
    if (i >= n4) return;
    float4 a = ((const float4*)src)[i];
    ushort4 o;
    o.x = f2bf(a.x); o.y = f2bf(a.y); o.z = f2bf(a.z); o.w = f2bf(a.w);
    ((ushort4*)dst)[i] = o;
}

// src: R x C fp32 row-major (R,C multiples of 64). dst: C x R bf16 row-major (ld_dst).
__global__ void transpose_cast_kernel(const float* __restrict__ src, int C,
                                      unsigned short* __restrict__ dst, int ld_dst) {
    __shared__ float t[64][65];
    int c0 = blockIdx.x * 64, r0 = blockIdx.y * 64;
    int tx = threadIdx.x, ty = threadIdx.y;   // 64 x 16
    #pragma unroll
    for (int i = 0; i < 64; i += 16)
        t[ty + i][tx] = src[(long)(r0 + ty + i) * C + c0 + tx];
    __syncthreads();
    #pragma unroll
    for (int i = 0; i < 64; i += 16)
        dst[(long)(c0 + ty + i) * ld_dst + r0 + tx] = f2bf(t[tx][ty + i]);
}

__global__ void concat_bias_kernel(const float* __restrict__ bq,
                                   const float* __restrict__ bkv,
                                   float* __restrict__ out) {
    int i = blockIdx.x * 256 + threadIdx.x;
    if (i < 2304) out[i] = (i < 768) ? bq[i] : bkv[i - 768];
}

// ---------------- bf16 MFMA GEMM: C = A @ B + bias ----------------
// A: M x K bf16 row-major (lda), staged in LDS via global_load_lds (XOR-swizzled).
// BT: N x K bf16 row-major == B^T; fragments loaded PER-LANE straight from
// global (L2-resident weights) — no LDS for B (halves LDS pipe pressure).
// Block tile (MI*32) x (NI*32), BK=64, 4 waves in 2x2; wave owns (MI*16)x(NI*16).
// KT_SPLIT (GEMM1 only): cols [768,1536) are k_x -> scatter to kT[h][d][row]
// (kT index = (col-768)*512 + row) instead of Cout, for coalesced attention.

template <int MI, int NI, bool OUT_BF16, bool XCD_SWZ, bool KT_SPLIT>
__global__ __launch_bounds__(256)
void gemm_bf16_kernel(const unsigned short* __restrict__ A, int lda,
                      const unsigned short* __restrict__ BT, int ldb,
                      const float* __restrict__ bias,
                      void* __restrict__ Cout, int ldc, int K,
                      int nx, int ypx, float* __restrict__ kT) {
    constexpr int TR = MI * 32;   // tile rows (M)
    constexpr int TC = NI * 32;   // tile cols (N)
    __shared__ unsigned short As[TR * 64];
    const int tid = threadIdx.x;
    const int w = tid >> 6, lane = tid & 63;
    const int lm = lane & 15, quad = lane >> 4;
    int tx, ty;
    if (XCD_SWZ) {
        int L = blockIdx.x;
        int xcd = L & 7, slot = L >> 3;
        tx = slot % nx;
        ty = slot / nx + xcd * ypx;
    } else {
        tx = blockIdx.x; ty = blockIdx.y;
    }
    const long tm = (long)ty * TR;
    const long tn = (long)tx * TC;
    const int m_off = (w & 1) * MI * 16, n_off = (w >> 1) * NI * 16;
    const int lrow8 = lane >> 3;                        // 0..7 row within 8-row chunk
    const int lcol_sw = (((lane & 7) ^ lrow8) * 8);     // swizzled global k-chunk (A only)

    // per-lane fixed B-fragment row pointers
    const unsigned short* bptr[NI];
    #pragma unroll
    for (int ni = 0; ni < NI; ++ni)
        bptr[ni] = BT + (tn + n_off + ni * 16 + lm) * (long)ldb + quad * 8;

    f32x4 acc[MI][NI];
    #pragma unroll
    for (int mi = 0; mi < MI; ++mi)
        #pragma unroll
        for (int ni = 0; ni < NI; ++ni) acc[mi][ni] = f32x4{0.f, 0.f, 0.f, 0.f};

    for (int k0 = 0; k0 < K; k0 += 64) {
        __syncthreads();   // previous stage's LDS reads done before overwrite
        #pragma unroll
        for (int i = 0; i < TR / 32; ++i) {
            int r0 = w * (TR / 4) + i * 8;
            const unsigned short* ga = A + (tm + r0 + lrow8) * lda + k0 + lcol_sw;
            __builtin_amdgcn_global_load_lds((gas_ptr)ga, (las_ptr)(As + r0 * 64), 16, 0, 0);
        }
        __syncthreads();   // drains A staging only (B loads issued after)
        #pragma unroll
        for (int kk = 0; kk < 2; ++kk) {
            bf16x8 af[MI], bfr[NI];
            #pragma unroll
            for (int ni = 0; ni < NI; ++ni)
                bfr[ni] = *(const bf16x8*)(bptr[ni] + k0 + kk * 32);
            #pragma unroll
            for (int mi = 0; mi < MI; ++mi) {
                int r = m_off + mi * 16 + lm;
                af[mi] = *(const bf16x8*)(As + r * 64 + (((kk * 4 + quad) ^ (r & 7)) * 8));
            }
            #pragma unroll
            for (int mi = 0; mi < MI; ++mi)
                #pragma unroll
                for (int ni = 0; ni < NI; ++ni)
                    acc[mi][ni] = __builtin_amdgcn_mfma_f32_16x16x32_bf16(
                        af[mi], bfr[ni], acc[mi][ni], 0, 0, 0);
        }
    }

    #pragma unroll
    for (int mi = 0; mi < MI; ++mi) {
        #pragma unroll
        for (int ni = 0; ni < NI; ++ni) {
            long col = tn + n_off + ni * 16 + lm;
            float bv = bias[col];
            #pragma unroll
            for (int r = 0; r < 4; ++r) {
                long row = tm + m_off + mi * 16 + quad * 4 + r;   // C/D: col=lane&15, row=quad*4+reg
                float v = acc[mi][ni][r] + bv;
                if (KT_SPLIT && col >= 768 && col < 1536) {
                    kT[(col - 768) * 512 + row] = v;
                } else if (OUT_BF16) {
                    ((unsigned short*)Cout)[row * ldc + col] = f2bf(v);
                } else {
                    ((float*)Cout)[row * ldc + col] = v;
                }
            }
        }
    }
}

// ---------------- fused asymmetric attention ----------------
// qkv: (B*N) x 2304 fp32  [q | (unused) | v_x] per row.
// kT:  768 x 512 fp32 — k_x transposed per head: kT[(h*64+d)*512 + b*256 + n].
// kvs: (B*N*M) x 1536 bf16 [k_s | v_s] per row.
// attn_out: (B*N) x 768 bf16.
// One block per (b,h,n), 320 threads (5 waves). Scores: t<256 -> sg[t], t>=256 -> sl[t-256].
__global__ __launch_bounds__(320)
void attn_kernel(const float* __restrict__ qkv,
                 const float* __restrict__ kT,
                 const unsigned short* __restrict__ kvs,
                 unsigned short* __restrict__ attn_out) {
    const int n = blockIdx.x, h = blockIdx.y, b = blockIdx.z;
    const int t = threadIdx.x;
    const int lane = t & 63, wid = t >> 6;
    __shared__ float q[64];
    __shared__ float wgt[320];
    __shared__ float red[8];
    __shared__ float part[5][64];

    const long row_bn = (long)(b * 256 + n);
    if (t < 64) q[t] = qkv[row_bn * 2304 + h * 64 + t];
    __syncthreads();

    float s;
    if (t < 256) {
        const float* kp = kT + (long)h * 64 * 512 + b * 256 + t;   // coalesced over t
        float acc = 0.f;
        #pragma unroll
        for (int d = 0; d < 64; ++d)
            acc += q[d] * kp[(long)d * 512];
        s = acc;
    } else {
        const int m = t - 256;
        const unsigned short* ksrow = kvs + (row_bn * 64 + m) * 1536 + h * 64;
        float acc = 0.f;
        #pragma unroll
        for (int d8 = 0; d8 < 8; ++d8) {
            bf16x8 k8 = *(const bf16x8*)(ksrow + d8 * 8);
            #pragma unroll
            for (int j = 0; j < 8; ++j)
                acc += q[d8 * 8 + j] * (float)k8[j];
        }
        s = acc;
    }
    s *= 0.125f;   // HD^-0.5

    // block max over 320
    float v = s;
    #pragma unroll
    for (int off = 32; off > 0; off >>= 1) v = fmaxf(v, __shfl_xor(v, off));
    if (lane == 0) red[wid] = v;
    __syncthreads();
    float mx = fmaxf(fmaxf(fmaxf(red[0], red[1]), fmaxf(red[2], red[3])), red[4]);
    float e = __expf(s - mx);

    // block sum over 320
    float v2 = e;
    #pragma unroll
    for (int off = 32; off > 0; off >>= 1) v2 += __shfl_xor(v2, off);
    __syncthreads();   // everyone done reading red before overwrite
    if (lane == 0) red[wid] = v2;
    __syncthreads();
    float denom = red[0] + red[1] + red[2] + red[3] + red[4];
    wgt[t] = e * (1.f / denom);
    __syncthreads();

    // output: waves 0..3 sum 64 global keys each (coalesced v_x row reads);
    // wave 4 sums the 64 sim values.
    const int d = lane, g = wid;
    float acc = 0.f;
    if (g < 4) {
        const float* vbase = qkv + 1536 + h * 64 + d;
        const int kk0 = b * 256 + g * 64;
        for (int kk = 0; kk < 64; ++kk)
            acc += wgt[g * 64 + kk] * vbase[(long)(kk0 + kk) * 2304];
    } else {
        const unsigned short* vsbase = kvs + row_bn * 64 * 1536 + 768 + h * 64 + d;
        #pragma unroll 4
        for (int m = 0; m < 64; ++m)
            acc += wgt[256 + m] * bf2f(vsbase[(long)m * 1536]);
    }
    part[g][d] = acc;
    __syncthreads();
    if (t < 64) {
        float o = part[0][t] + part[1][t] + part[2][t] + part[3][t] + part[4][t];
        attn_out[row_bn * 768 + h * 64 + t] = f2bf(o);
    }
}

// ---------------- launch ----------------

extern "C" void kernel_launch(void* const* d_in, const int* in_sizes, int n_in,
                              void* d_out, int out_size, void* d_ws, size_t ws_size,
                              hipStream_t stream) {
    const float* x   = (const float*)d_in[0];   // (2,256,768)
    const float* sim = (const float*)d_in[1];   // (2,256,64,768)
    const float* Wq  = (const float*)d_in[2];   // (768,768)
    const float* bq  = (const float*)d_in[3];   // (768)
    const float* Wkv = (const float*)d_in[4];   // (768,1536)
    const float* bkv = (const float*)d_in[5];   // (1536)
    const float* Wp  = (const float*)d_in[6];   // (768,768)
    const float* bp  = (const float*)d_in[7];   // (768)
    float* out = (float*)d_out;                 // (2,256,768) fp32

    char* ws = (char*)d_ws;
    size_t off = 0;
    auto alloc = [&](size_t bytes) {
        char* p = ws + off;
        off += (bytes + 255) & ~(size_t)255;
        return p;
    };
    unsigned short* simb  = (unsigned short*)alloc(32768UL * 768 * 2);   // sim bf16
    unsigned short* kvs   = (unsigned short*)alloc(32768UL * 1536 * 2);  // kv_s bf16
    unsigned short* xb    = (unsigned short*)alloc(512UL * 768 * 2);     // x bf16
    unsigned short* w1t   = (unsigned short*)alloc(2304UL * 768 * 2);    // [Wq|Wkv]^T bf16
    unsigned short* wpt   = (unsigned short*)alloc(768UL * 768 * 2);     // Wp^T bf16
    float*          qkv   = (float*)alloc(512UL * 2304 * 4);             // q|.|v_x fp32
    float*          kTbuf = (float*)alloc(768UL * 512 * 4);              // k_x^T per head
    unsigned short* attnb = (unsigned short*)alloc(512UL * 768 * 2);     // attn out bf16
    float*          bias1 = (float*)alloc(2304UL * 4);                   // [bq|bkv]

    // casts / transposes
    cast_bf16_kernel<<<(512L * 768 / 4 + 255) / 256, 256, 0, stream>>>(x, xb, 512L * 768 / 4);
    cast_bf16_kernel<<<(32768L * 768 / 4 + 255) / 256, 256, 0, stream>>>(sim, simb, 32768L * 768 / 4);
    transpose_cast_kernel<<<dim3(12, 12), dim3(64, 16), 0, stream>>>(Wq, 768, w1t, 768);
    transpose_cast_kernel<<<dim3(24, 12), dim3(64, 16), 0, stream>>>(Wkv, 1536, w1t + 768L * 768, 768);
    transpose_cast_kernel<<<dim3(12, 12), dim3(64, 16), 0, stream>>>(Wp, 768, wpt, 768);
    concat_bias_kernel<<<9, 256, 0, stream>>>(bq, bkv, bias1);

    // GEMM1: qkv = x @ [Wq|Wkv] + [bq|bkv]  (512 x 2304, K=768), k_x cols -> kT
    gemm_bf16_kernel<2, 2, false, false, true><<<dim3(36, 8), 256, 0, stream>>>(
        xb, 768, w1t, 768, bias1, qkv, 2304, 768, 0, 0, kTbuf);

    // GEMM2: kv_s = sim @ Wkv + bkv  (32768 x 1536, K=768) -> bf16, 128x128 tiles,
    // XCD-swizzled 1-D grid: 3072 blocks = 8 XCDs x (12 x-tiles x 32 y-tiles)
    gemm_bf16_kernel<4, 4, true, true, false><<<3072, 256, 0, stream>>>(
        simb, 768, w1t + 768L * 768, 768, bkv, kvs, 1536, 768, 12, 32, nullptr);

    // fused attention
    attn_kernel<<<dim3(256, 12, 2), 320, 0, stream>>>(qkv, kTbuf, kvs, attnb);

    // GEMM3: out = attn @ Wp + bp   (512 x 768, K=768) -> fp32
    gemm_bf16_kernel<2, 2, false, false, false><<<dim3(12, 8), 256, 0, stream>>>(
        attnb, 768, wpt, 768, bp, out, 768, 768, 0, 0, nullptr);
}

// Round 4
// 429.376 us; speedup vs baseline: 1.1000x; 1.1000x over previous
//
#include <hip/hip_runtime.h>
#include <stdint.h>

#define DEV_INLINE __device__ __forceinline__

typedef __bf16 bf16x8 __attribute__((ext_vector_type(8)));
typedef float f32x4 __attribute__((ext_vector_type(4)));

typedef const __attribute__((address_space(1))) void* gas_ptr;
typedef __attribute__((address_space(3))) void* las_ptr;

DEV_INLINE unsigned short f2bf(float f) {
    union { float f; unsigned u; } v; v.f = f;
    unsigned r = v.u + 0x7fffu + ((v.u >> 16) & 1u);   // RNE
    return (unsigned short)(r >> 16);
}
DEV_INLINE float bf2f(unsigned short u) {
    union { unsigned u; float f; } v; v.u = ((unsigned)u) << 16;
    return v.f;
}

// ---------------- casts ----------------

__global__ void cast_bf16_kernel(const float* __restrict__ src,
                                 unsigned short* __restrict__ dst, long n4) {
    long i = (long)blockIdx.x * blockDim.x + threadIdx.x;
    if (i >= n4) return;
    float4 a = ((const float4*)src)[i];
    ushort4 o;
    o.x = f2bf(a.x); o.y = f2bf(a.y); o.z = f2bf(a.z); o.w = f2bf(a.w);
    ((ushort4*)dst)[i] = o;
}

// src: R x C fp32 row-major (R,C multiples of 64). dst: C x R bf16 row-major (ld_dst).
__global__ void transpose_cast_kernel(const float* __restrict__ src, int C,
                                      unsigned short* __restrict__ dst, int ld_dst) {
    __shared__ float t[64][65];
    int c0 = blockIdx.x * 64, r0 = blockIdx.y * 64;
    int tx = threadIdx.x, ty = threadIdx.y;   // 64 x 16
    #pragma unroll
    for (int i = 0; i < 64; i += 16)
        t[ty + i][tx] = src[(long)(r0 + ty + i) * C + c0 + tx];
    __syncthreads();
    #pragma unroll
    for (int i = 0; i < 64; i += 16)
        dst[(long)(c0 + ty + i) * ld_dst + r0 + tx] = f2bf(t[tx][ty + i]);
}

__global__ void concat_bias_kernel(const float* __restrict__ bq,
                                   const float* __restrict__ bkv,
                                   float* __restrict__ out) {
    int i = blockIdx.x * 256 + threadIdx.x;
    if (i < 2304) out[i] = (i < 768) ? bq[i] : bkv[i - 768];
}

// ---------------- bf16 MFMA GEMM: C = A @ B + bias ----------------
// A: M x K bf16 row-major (lda). BT: N x K bf16 row-major (ldb) == B^T.
// BOTH operands staged through LDS via global_load_lds w=16 (coalesced; R2
// showed per-lane global B-fragments scatter to 64 segments/instr and stall).
// 4 waves in WAVES_M x (4/WAVES_M) grid; wave owns (WM*16) x (WN*16).
// LDS chunk-XOR swizzle (chunk=16B): position p of row r holds k-chunk p^(r&7)
// -> zero bank conflicts (verified R1).
// KT_SPLIT (GEMM1): cols [768,1536) scatter to kT[(col-768)*512+row].

template <int WM, int WN, int WAVES_M, bool OUT_BF16, bool XCD_SWZ, bool KT_SPLIT>
__global__ __launch_bounds__(256)
void gemm_bf16_kernel(const unsigned short* __restrict__ A, int lda,
                      const unsigned short* __restrict__ BT, int ldb,
                      const float* __restrict__ bias,
                      void* __restrict__ Cout, int ldc, int K,
                      int nx, int ypx, float* __restrict__ kT) {
    constexpr int TR = WAVES_M * WM * 16;         // tile rows (M)
    constexpr int TC = (4 / WAVES_M) * WN * 16;   // tile cols (N)
    __shared__ unsigned short As[TR * 64];
    __shared__ unsigned short Bs[TC * 64];
    const int tid = threadIdx.x;
    const int w = tid >> 6, lane = tid & 63;
    const int lm = lane & 15, quad = lane >> 4;
    int tx, ty;
    if (XCD_SWZ) {
        int L = blockIdx.x;
        int xcd = L & 7, slot = L >> 3;
        tx = slot % nx;
        ty = slot / nx + xcd * ypx;
    } else {
        tx = blockIdx.x; ty = blockIdx.y;
    }
    const long tm = (long)ty * TR;
    const long tn = (long)tx * TC;
    const int m_off = (w % WAVES_M) * WM * 16;
    const int n_off = (w / WAVES_M) * WN * 16;
    const int lrow8 = lane >> 3;                        // 0..7 row within 8-row chunk
    const int lcol_sw = (((lane & 7) ^ lrow8) * 8);     // swizzled global k-chunk

    f32x4 acc[WM][WN];
    #pragma unroll
    for (int mi = 0; mi < WM; ++mi)
        #pragma unroll
        for (int ni = 0; ni < WN; ++ni) acc[mi][ni] = f32x4{0.f, 0.f, 0.f, 0.f};

    for (int k0 = 0; k0 < K; k0 += 64) {
        __syncthreads();   // previous stage's LDS reads done before overwrite
        #pragma unroll
        for (int i = 0; i < TR / 32; ++i) {
            int r0 = w * (TR / 4) + i * 8;
            const unsigned short* ga = A + (tm + r0 + lrow8) * lda + k0 + lcol_sw;
            __builtin_amdgcn_global_load_lds((gas_ptr)ga, (las_ptr)(As + r0 * 64), 16, 0, 0);
        }
        #pragma unroll
        for (int i = 0; i < TC / 32; ++i) {
            int r0 = w * (TC / 4) + i * 8;
            const unsigned short* gb = BT + (tn + r0 + lrow8) * ldb + k0 + lcol_sw;
            __builtin_amdgcn_global_load_lds((gas_ptr)gb, (las_ptr)(Bs + r0 * 64), 16, 0, 0);
        }
        __syncthreads();
        #pragma unroll
        for (int kk = 0; kk < 2; ++kk) {
            bf16x8 af[WM], bfr[WN];
            #pragma unroll
            for (int mi = 0; mi < WM; ++mi) {
                int r = m_off + mi * 16 + lm;
                af[mi] = *(const bf16x8*)(As + r * 64 + (((kk * 4 + quad) ^ (r & 7)) * 8));
            }
            #pragma unroll
            for (int ni = 0; ni < WN; ++ni) {
                int r = n_off + ni * 16 + lm;
                bfr[ni] = *(const bf16x8*)(Bs + r * 64 + (((kk * 4 + quad) ^ (r & 7)) * 8));
            }
            #pragma unroll
            for (int mi = 0; mi < WM; ++mi)
                #pragma unroll
                for (int ni = 0; ni < WN; ++ni)
                    acc[mi][ni] = __builtin_amdgcn_mfma_f32_16x16x32_bf16(
                        af[mi], bfr[ni], acc[mi][ni], 0, 0, 0);
        }
    }

    #pragma unroll
    for (int mi = 0; mi < WM; ++mi) {
        #pragma unroll
        for (int ni = 0; ni < WN; ++ni) {
            long col = tn + n_off + ni * 16 + lm;
            float bv = bias[col];
            #pragma unroll
            for (int r = 0; r < 4; ++r) {
                long row = tm + m_off + mi * 16 + quad * 4 + r;   // C/D: col=lane&15, row=quad*4+reg
                float v = acc[mi][ni][r] + bv;
                if (KT_SPLIT && col >= 768 && col < 1536) {
                    kT[(col - 768) * 512 + row] = v;
                } else if (OUT_BF16) {
                    ((unsigned short*)Cout)[row * ldc + col] = f2bf(v);
                } else {
                    ((float*)Cout)[row * ldc + col] = v;
                }
            }
        }
    }
}

// ---------------- fused asymmetric attention ----------------
// qkv: (B*N) x 2304 fp32  [q | (unused) | v_x] per row.
// kT:  768 x 512 fp32 — k_x transposed per head: kT[(h*64+d)*512 + b*256 + n].
// kvs: (B*N*M) x 1536 bf16 [k_s | v_s] per row.
// attn_out: (B*N) x 768 bf16.
// One block per (b,h,n), 320 threads (5 waves). Scores: t<256 -> sg[t], t>=256 -> sl[t-256].
__global__ __launch_bounds__(320)
void attn_kernel(const float* __restrict__ qkv,
                 const float* __restrict__ kT,
                 const unsigned short* __restrict__ kvs,
                 unsigned short* __restrict__ attn_out) {
    const int n = blockIdx.x, h = blockIdx.y, b = blockIdx.z;
    const int t = threadIdx.x;
    const int lane = t & 63, wid = t >> 6;
    __shared__ float q[64];
    __shared__ float wgt[320];
    __shared__ float red[8];
    __shared__ float part[5][64];

    const long row_bn = (long)(b * 256 + n);
    if (t < 64) q[t] = qkv[row_bn * 2304 + h * 64 + t];
    __syncthreads();

    float s;
    if (t < 256) {
        const float* kp = kT + (long)h * 64 * 512 + b * 256 + t;   // coalesced over t
        float acc = 0.f;
        #pragma unroll
        for (int d = 0; d < 64; ++d)
            acc += q[d] * kp[(long)d * 512];
        s = acc;
    } else {
        const int m = t - 256;
        const unsigned short* ksrow = kvs + (row_bn * 64 + m) * 1536 + h * 64;
        float acc = 0.f;
        #pragma unroll
        for (int d8 = 0; d8 < 8; ++d8) {
            bf16x8 k8 = *(const bf16x8*)(ksrow + d8 * 8);
            #pragma unroll
            for (int j = 0; j < 8; ++j)
                acc += q[d8 * 8 + j] * (float)k8[j];
        }
        s = acc;
    }
    s *= 0.125f;   // HD^-0.5

    // block max over 320
    float v = s;
    #pragma unroll
    for (int off = 32; off > 0; off >>= 1) v = fmaxf(v, __shfl_xor(v, off));
    if (lane == 0) red[wid] = v;
    __syncthreads();
    float mx = fmaxf(fmaxf(fmaxf(red[0], red[1]), fmaxf(red[2], red[3])), red[4]);
    float e = __expf(s - mx);

    // block sum over 320
    float v2 = e;
    #pragma unroll
    for (int off = 32; off > 0; off >>= 1) v2 += __shfl_xor(v2, off);
    __syncthreads();   // everyone done reading red before overwrite
    if (lane == 0) red[wid] = v2;
    __syncthreads();
    float denom = red[0] + red[1] + red[2] + red[3] + red[4];
    wgt[t] = e * (1.f / denom);
    __syncthreads();

    // output: waves 0..3 sum 64 global keys each (coalesced v_x row reads);
    // wave 4 sums the 64 sim values.
    const int d = lane, g = wid;
    float acc = 0.f;
    if (g < 4) {
        const float* vbase = qkv + 1536 + h * 64 + d;
        const int kk0 = b * 256 + g * 64;
        for (int kk = 0; kk < 64; ++kk)
            acc += wgt[g * 64 + kk] * vbase[(long)(kk0 + kk) * 2304];
    } else {
        const unsigned short* vsbase = kvs + row_bn * 64 * 1536 + 768 + h * 64 + d;
        #pragma unroll 4
        for (int m = 0; m < 64; ++m)
            acc += wgt[256 + m] * bf2f(vsbase[(long)m * 1536]);
    }
    part[g][d] = acc;
    __syncthreads();
    if (t < 64) {
        float o = part[0][t] + part[1][t] + part[2][t] + part[3][t] + part[4][t];
        attn_out[row_bn * 768 + h * 64 + t] = f2bf(o);
    }
}

// ---------------- launch ----------------

extern "C" void kernel_launch(void* const* d_in, const int* in_sizes, int n_in,
                              void* d_out, int out_size, void* d_ws, size_t ws_size,
                              hipStream_t stream) {
    const float* x   = (const float*)d_in[0];   // (2,256,768)
    const float* sim = (const float*)d_in[1];   // (2,256,64,768)
    const float* Wq  = (const float*)d_in[2];   // (768,768)
    const float* bq  = (const float*)d_in[3];   // (768)
    const float* Wkv = (const float*)d_in[4];   // (768,1536)
    const float* bkv = (const float*)d_in[5];   // (1536)
    const float* Wp  = (const float*)d_in[6];   // (768,768)
    const float* bp  = (const float*)d_in[7];   // (768)
    float* out = (float*)d_out;                 // (2,256,768) fp32

    char* ws = (char*)d_ws;
    size_t off = 0;
    auto alloc = [&](size_t bytes) {
        char* p = ws + off;
        off += (bytes + 255) & ~(size_t)255;
        return p;
    };
    unsigned short* simb  = (unsigned short*)alloc(32768UL * 768 * 2);   // sim bf16
    unsigned short* kvs   = (unsigned short*)alloc(32768UL * 1536 * 2);  // kv_s bf16
    unsigned short* xb    = (unsigned short*)alloc(512UL * 768 * 2);     // x bf16
    unsigned short* w1t   = (unsigned short*)alloc(2304UL * 768 * 2);    // [Wq|Wkv]^T bf16
    unsigned short* wpt   = (unsigned short*)alloc(768UL * 768 * 2);     // Wp^T bf16
    float*          qkv   = (float*)alloc(512UL * 2304 * 4);             // q|.|v_x fp32
    float*          kTbuf = (float*)alloc(768UL * 512 * 4);              // k_x^T per head
    unsigned short* attnb = (unsigned short*)alloc(512UL * 768 * 2);     // attn out bf16
    float*          bias1 = (float*)alloc(2304UL * 4);                   // [bq|bkv]

    // casts / transposes
    cast_bf16_kernel<<<(512L * 768 / 4 + 255) / 256, 256, 0, stream>>>(x, xb, 512L * 768 / 4);
    cast_bf16_kernel<<<(32768L * 768 / 4 + 255) / 256, 256, 0, stream>>>(sim, simb, 32768L * 768 / 4);
    transpose_cast_kernel<<<dim3(12, 12), dim3(64, 16), 0, stream>>>(Wq, 768, w1t, 768);
    transpose_cast_kernel<<<dim3(24, 12), dim3(64, 16), 0, stream>>>(Wkv, 1536, w1t + 768L * 768, 768);
    transpose_cast_kernel<<<dim3(12, 12), dim3(64, 16), 0, stream>>>(Wp, 768, wpt, 768);
    concat_bias_kernel<<<9, 256, 0, stream>>>(bq, bkv, bias1);

    // GEMM1: qkv = x @ [Wq|Wkv] + [bq|bkv]  (512 x 2304, K=768), 64x64 tiles,
    // k_x cols scattered to kT for coalesced attention scores
    gemm_bf16_kernel<2, 2, 2, false, false, true><<<dim3(36, 8), 256, 0, stream>>>(
        xb, 768, w1t, 768, bias1, qkv, 2304, 768, 0, 0, kTbuf);

    // GEMM2: kv_s = sim @ Wkv + bkv  (32768 x 1536, K=768) -> bf16.
    // 256x128 tiles (wave = 64x128 strip): LDS-read ~1130cy < MFMA ~1240cy per k-iter.
    // XCD-swizzled 1-D grid: 1536 blocks = 8 XCDs x (12 x-tiles x 16 y-tiles)
    gemm_bf16_kernel<4, 8, 4, true, true, false><<<1536, 256, 0, stream>>>(
        simb, 768, w1t + 768L * 768, 768, bkv, kvs, 1536, 768, 12, 16, nullptr);

    // fused attention (kT-coalesced global scores)
    attn_kernel<<<dim3(256, 12, 2), 320, 0, stream>>>(qkv, kTbuf, kvs, attnb);

    // GEMM3: out = attn @ Wp + bp   (512 x 768, K=768) -> fp32, 64x64 tiles
    gemm_bf16_kernel<2, 2, 2, false, false, false><<<dim3(12, 8), 256, 0, stream>>>(
        attnb, 768, wpt, 768, bp, out, 768, 768, 0, 0, nullptr);
}

// Round 5
// 308.673 us; speedup vs baseline: 1.5302x; 1.3910x over previous
//
#include <hip/hip_runtime.h>
#include <stdint.h>

#define DEV_INLINE __device__ __forceinline__

typedef __bf16 bf16x8 __attribute__((ext_vector_type(8)));
typedef float f32x4 __attribute__((ext_vector_type(4)));

typedef const __attribute__((address_space(1))) void* gas_ptr;
typedef __attribute__((address_space(3))) void* las_ptr;

DEV_INLINE unsigned short f2bf(float f) {
    union { float f; unsigned u; } v; v.f = f;
    unsigned r = v.u + 0x7fffu + ((v.u >> 16) & 1u);   // RNE
    return (unsigned short)(r >> 16);
}
DEV_INLINE float bf2f(unsigned short u) {
    union { unsigned u; float f; } v; v.u = ((unsigned)u) << 16;
    return v.f;
}

// ---------------- casts ----------------

__global__ void cast_bf16_kernel(const float* __restrict__ src,
                                 unsigned short* __restrict__ dst, long n4) {
    long i = (long)blockIdx.x * blockDim.x + threadIdx.x;
    if (i >= n4) return;
    float4 a = ((const float4*)src)[i];
    ushort4 o;
    o.x = f2bf(a.x); o.y = f2bf(a.y); o.z = f2bf(a.z); o.w = f2bf(a.w);
    ((ushort4*)dst)[i] = o;
}

// src: R x C fp32 row-major. dst: C x R bf16 row-major (ld_dst). R,C mult of 64.
__global__ void transpose_cast_kernel(const float* __restrict__ src, int C,
                                      unsigned short* __restrict__ dst, int ld_dst) {
    __shared__ float t[64][65];
    int c0 = blockIdx.x * 64, r0 = blockIdx.y * 64;
    int tx = threadIdx.x, ty = threadIdx.y;   // 64 x 16
    #pragma unroll
    for (int i = 0; i < 64; i += 16)
        t[ty + i][tx] = src[(long)(r0 + ty + i) * C + c0 + tx];
    __syncthreads();
    #pragma unroll
    for (int i = 0; i < 64; i += 16)
        dst[(long)(c0 + ty + i) * ld_dst + r0 + tx] = f2bf(t[tx][ty + i]);
}

// bias1[0:2304] = [bq|bkv]; zerobuf[0:768] = 0
__global__ void bias_init_kernel(const float* __restrict__ bq,
                                 const float* __restrict__ bkv,
                                 float* __restrict__ bias1,
                                 float* __restrict__ zerobuf) {
    int i = blockIdx.x * 256 + threadIdx.x;
    if (i < 2304) bias1[i] = (i < 768) ? bq[i] : bkv[i - 768];
    else if (i < 3072) zerobuf[i - 2304] = 0.f;
}

// ---------------- bf16 MFMA GEMM (R1-proven core) ----------------
// A: M x K bf16 row-major (lda). BT: N x K bf16 row-major (ldb) == B^T.
// Both staged via global_load_lds w=16, XOR chunk swizzle (0 bank conflicts).
// 64x64 tile (<2,2,2>), 4 waves in 2x2.
// MODE 0: Cout fp32 = acc + bias.
// MODE 1 (GEMM1): col<768 -> qkv fp32 + qb bf16; 768..1535 -> kT[(col-768)*512+row];
//                 >=1536 -> qkv fp32. (bias applied to all)
// MODE 2: bf16 out with z-offsets: A+=z*aZ, BT+=z*btZ,
//         out idx = z*cZ + row*ldc + z*colZ + col; optional fp32 cin accumulate.

template <int WM, int WN, int WAVES_M, int MODE>
__global__ __launch_bounds__(256)
void gemm_bf16_kernel(const unsigned short* __restrict__ A, int lda,
                      const unsigned short* __restrict__ BT, int ldb,
                      const float* __restrict__ bias,
                      void* __restrict__ Cout, int ldc, int K,
                      float* __restrict__ auxF, unsigned short* __restrict__ auxU,
                      const float* __restrict__ cin,
                      long aZ, long btZ, long cZ, int colZ) {
    constexpr int TR = WAVES_M * WM * 16;
    constexpr int TC = (4 / WAVES_M) * WN * 16;
    __shared__ unsigned short As[TR * 64];
    __shared__ unsigned short Bs[TC * 64];
    const int tid = threadIdx.x;
    const int w = tid >> 6, lane = tid & 63;
    const int lm = lane & 15, quad = lane >> 4;
    const int z = blockIdx.z;
    A  += (long)z * aZ;
    BT += (long)z * btZ;
    const long tm = (long)blockIdx.y * TR;
    const long tn = (long)blockIdx.x * TC;
    const int m_off = (w % WAVES_M) * WM * 16;
    const int n_off = (w / WAVES_M) * WN * 16;
    const int lrow8 = lane >> 3;
    const int lcol_sw = (((lane & 7) ^ lrow8) * 8);

    f32x4 acc[WM][WN];
    #pragma unroll
    for (int mi = 0; mi < WM; ++mi)
        #pragma unroll
        for (int ni = 0; ni < WN; ++ni) acc[mi][ni] = f32x4{0.f, 0.f, 0.f, 0.f};

    for (int k0 = 0; k0 < K; k0 += 64) {
        __syncthreads();
        #pragma unroll
        for (int i = 0; i < TR / 32; ++i) {
            int r0 = w * (TR / 4) + i * 8;
            const unsigned short* ga = A + (tm + r0 + lrow8) * lda + k0 + lcol_sw;
            __builtin_amdgcn_global_load_lds((gas_ptr)ga, (las_ptr)(As + r0 * 64), 16, 0, 0);
        }
        #pragma unroll
        for (int i = 0; i < TC / 32; ++i) {
            int r0 = w * (TC / 4) + i * 8;
            const unsigned short* gb = BT + (tn + r0 + lrow8) * ldb + k0 + lcol_sw;
            __builtin_amdgcn_global_load_lds((gas_ptr)gb, (las_ptr)(Bs + r0 * 64), 16, 0, 0);
        }
        __syncthreads();
        #pragma unroll
        for (int kk = 0; kk < 2; ++kk) {
            bf16x8 af[WM], bfr[WN];
            #pragma unroll
            for (int mi = 0; mi < WM; ++mi) {
                int r = m_off + mi * 16 + lm;
                af[mi] = *(const bf16x8*)(As + r * 64 + (((kk * 4 + quad) ^ (r & 7)) * 8));
            }
            #pragma unroll
            for (int ni = 0; ni < WN; ++ni) {
                int r = n_off + ni * 16 + lm;
                bfr[ni] = *(const bf16x8*)(Bs + r * 64 + (((kk * 4 + quad) ^ (r & 7)) * 8));
            }
            #pragma unroll
            for (int mi = 0; mi < WM; ++mi)
                #pragma unroll
                for (int ni = 0; ni < WN; ++ni)
                    acc[mi][ni] = __builtin_amdgcn_mfma_f32_16x16x32_bf16(
                        af[mi], bfr[ni], acc[mi][ni], 0, 0, 0);
        }
    }

    #pragma unroll
    for (int mi = 0; mi < WM; ++mi) {
        #pragma unroll
        for (int ni = 0; ni < WN; ++ni) {
            long col = tn + n_off + ni * 16 + lm;
            float bv = bias[col];
            #pragma unroll
            for (int r = 0; r < 4; ++r) {
                long row = tm + m_off + mi * 16 + quad * 4 + r;   // C/D: col=lane&15, row=quad*4+reg
                float v = acc[mi][ni][r] + bv;
                if (MODE == 0) {
                    ((float*)Cout)[row * ldc + col] = v;
                } else if (MODE == 1) {
                    if (col < 768) {
                        ((float*)Cout)[row * ldc + col] = v;
                        auxU[row * 768 + col] = f2bf(v);            // qb
                    } else if (col < 1536) {
                        auxF[(col - 768) * 512 + row] = v;          // kT
                    } else {
                        ((float*)Cout)[row * ldc + col] = v;
                    }
                } else {   // MODE 2
                    long idx2 = row * (long)ldc + (long)z * colZ + col;
                    if (cin) v += cin[idx2];
                    ((unsigned short*)Cout)[(long)z * cZ + idx2] = f2bf(v);
                }
            }
        }
    }
}

// ---------------- B1: scores + softmax + out_g ----------------
// Block per (b,n): 768 threads (12 waves, one per head for softmax/out_g).
// sl[h][m] = qW[h]·sim[b,n,m,:] + q[h]·bkv_k[h]   (reassociated local scores)
// sg[h][k] = q[h]·k_x[b,k,h]  (via kT, coalesced)
// softmax over 320 per h; out_g[h] = sum_k ag·v_x + almass[h]*bkv_v[h] -> outg fp32
// al (normalized local weights) -> algl global for B2.
__global__ __launch_bounds__(768)
void attn_b1_kernel(const float* __restrict__ sim,
                    const float* __restrict__ qkv,
                    const float* __restrict__ kT,
                    const unsigned short* __restrict__ qWb,
                    const float* __restrict__ bkv,
                    float* __restrict__ outg,
                    float* __restrict__ algl) {
    __shared__ float qW_f[12][772];   // pad: stride 772 words % 32 == 4 -> 2-deep banks
    __shared__ float q_l[12][64];
    __shared__ float sc[12][321];     // scores then normalized weights (stride%32==1)
    __shared__ float slb[12], alm[12];

    const int t = threadIdx.x;
    const int lane = t & 63, w = t >> 6;
    const int n_ = blockIdx.y * 256 + blockIdx.x;   // b*256 + n

    // P0: load qW (bf16->fp32) and q
    #pragma unroll
    for (int h = 0; h < 12; ++h)
        qW_f[h][t] = bf2f(qWb[((long)h * 512 + n_) * 768 + t]);
    q_l[t >> 6][t & 63] = qkv[(long)n_ * 2304 + t];   // first 768 cols = q
    __syncthreads();

    if (t < 12) {   // sl bias: q[h]·bkv_k[h]
        float s = 0.f;
        #pragma unroll 8
        for (int d = 0; d < 64; ++d) s += q_l[t][d] * bkv[t * 64 + d];
        slb[t] = s;
    }

    // P2: sl dots — thread (m = t/12, h = t%12); 12 lanes share each sim row (dedup)
    {
        const int m = t / 12, h = t % 12;
        const float* srow = sim + ((long)n_ * 64 + m) * 768;
        float a0 = 0.f, a1 = 0.f, a2 = 0.f, a3 = 0.f;
        #pragma unroll 8
        for (int c = 0; c < 768; c += 4) {
            float4 s4 = *(const float4*)(srow + c);
            const float* qw = &qW_f[h][c];
            a0 += qw[0] * s4.x; a1 += qw[1] * s4.y;
            a2 += qw[2] * s4.z; a3 += qw[3] * s4.w;
        }
        float dot = (a0 + a1) + (a2 + a3);
        __syncthreads();   // slb ready
        sc[h][256 + m] = (dot + slb[h]) * 0.125f;
    }

    // P3: sg dots over kT (coalesced in k)
    #pragma unroll
    for (int j = 0; j < 4; ++j) {
        int id = j * 768 + t;
        int h = id >> 8, k = id & 255;
        const float* kp = kT + (long)h * 64 * 512 + blockIdx.y * 256 + k;
        float acc = 0.f;
        #pragma unroll 8
        for (int d = 0; d < 64; ++d)
            acc += q_l[h][d] * kp[(long)d * 512];
        sc[h][k] = acc * 0.125f;
    }
    __syncthreads();

    // P4: softmax over 320 (wave w handles head h=w); 5 scores per lane
    {
        const int h = w;
        float v0 = sc[h][lane], v1 = sc[h][lane + 64], v2 = sc[h][lane + 128],
              v3 = sc[h][lane + 192], v4 = sc[h][lane + 256];
        float mx = fmaxf(fmaxf(fmaxf(v0, v1), fmaxf(v2, v3)), v4);
        #pragma unroll
        for (int off = 32; off > 0; off >>= 1) mx = fmaxf(mx, __shfl_xor(mx, off));
        float e0 = __expf(v0 - mx), e1 = __expf(v1 - mx), e2 = __expf(v2 - mx),
              e3 = __expf(v3 - mx), e4 = __expf(v4 - mx);
        float s = e0 + e1 + e2 + e3 + e4;
        #pragma unroll
        for (int off = 32; off > 0; off >>= 1) s += __shfl_xor(s, off);
        float inv = __frcp_rn(s);
        sc[h][lane] = e0 * inv; sc[h][lane + 64] = e1 * inv;
        sc[h][lane + 128] = e2 * inv; sc[h][lane + 192] = e3 * inv;
        float al = e4 * inv;
        sc[h][lane + 256] = al;
        algl[(long)n_ * 768 + h * 64 + lane] = al;
        float am = al;
        #pragma unroll
        for (int off = 32; off > 0; off >>= 1) am += __shfl_xor(am, off);
        if (lane == 0) alm[h] = am;
    }
    // wave w wrote sc[w][*] and alm[w]; P5 reads only head w -> no barrier needed

    // P5: out_g (wave w = head, lane = d), v_x coalesced
    {
        const int h = w, d = lane;
        const float* vbase = qkv + 1536 + h * 64 + d + (long)blockIdx.y * 256 * 2304;
        float acc = 0.f;
        #pragma unroll 8
        for (int k = 0; k < 256; ++k)
            acc += sc[h][k] * vbase[(long)k * 2304];
        acc += alm[h] * bkv[768 + h * 64 + d];
        outg[(long)n_ * 768 + h * 64 + d] = acc;
    }
}

// ---------------- B2: simbar[h][n'][c] = sum_m al[h][m] * sim[n',m,c] ----------------
// Block per (b,n), 256 threads; thread owns cols {t, t+256, t+512}.
__global__ __launch_bounds__(256)
void attn_b2_kernel(const float* __restrict__ sim,
                    const float* __restrict__ algl,
                    unsigned short* __restrict__ simbar) {
    __shared__ float al_l[768];
    const int t = threadIdx.x;
    const int n_ = blockIdx.y * 256 + blockIdx.x;
    al_l[t] = algl[(long)n_ * 768 + t];
    al_l[t + 256] = algl[(long)n_ * 768 + t + 256];
    al_l[t + 512] = algl[(long)n_ * 768 + t + 512];
    __syncthreads();

    float acc[12][3] = {};
    const float* sbase = sim + (long)n_ * 64 * 768;
    for (int m = 0; m < 64; ++m) {
        float s0 = sbase[(long)m * 768 + t];
        float s1 = sbase[(long)m * 768 + t + 256];
        float s2 = sbase[(long)m * 768 + t + 512];
        #pragma unroll
        for (int h = 0; h < 12; ++h) {
            float a = al_l[h * 64 + m];
            acc[h][0] += a * s0; acc[h][1] += a * s1; acc[h][2] += a * s2;
        }
    }
    #pragma unroll
    for (int h = 0; h < 12; ++h) {
        unsigned short* dst = simbar + ((long)h * 512 + n_) * 768;
        dst[t] = f2bf(acc[h][0]);
        dst[t + 256] = f2bf(acc[h][1]);
        dst[t + 512] = f2bf(acc[h][2]);
    }
}

// ---------------- launch ----------------

extern "C" void kernel_launch(void* const* d_in, const int* in_sizes, int n_in,
                              void* d_out, int out_size, void* d_ws, size_t ws_size,
                              hipStream_t stream) {
    const float* x   = (const float*)d_in[0];   // (2,256,768)
    const float* sim = (const float*)d_in[1];   // (2,256,64,768)
    const float* Wq  = (const float*)d_in[2];   // (768,768)
    const float* bq  = (const float*)d_in[3];   // (768)
    const float* Wkv = (const float*)d_in[4];   // (768,1536)
    const float* bkv = (const float*)d_in[5];   // (1536)
    const float* Wp  = (const float*)d_in[6];   // (768,768)
    const float* bp  = (const float*)d_in[7];   // (768)
    float* out = (float*)d_out;                 // (2,256,768) fp32

    char* ws = (char*)d_ws;
    size_t off = 0;
    auto alloc = [&](size_t bytes) {
        char* p = ws + off;
        off += (bytes + 255) & ~(size_t)255;
        return p;
    };
    unsigned short* xb     = (unsigned short*)alloc(512UL * 768 * 2);     // x bf16
    unsigned short* w1t    = (unsigned short*)alloc(2304UL * 768 * 2);    // [Wq|Wkv]^T bf16
    unsigned short* wkvb   = (unsigned short*)alloc(768UL * 1536 * 2);    // Wkv bf16 (untransposed)
    unsigned short* wpt    = (unsigned short*)alloc(768UL * 768 * 2);     // Wp^T bf16
    float*          qkv    = (float*)alloc(512UL * 2304 * 4);             // q|.|v_x fp32
    float*          kTbuf  = (float*)alloc(768UL * 512 * 4);              // k_x^T per head
    unsigned short* qb     = (unsigned short*)alloc(512UL * 768 * 2);     // q bf16
    unsigned short* qWb    = (unsigned short*)alloc(12UL * 512 * 768 * 2);// qW bf16 [h][n'][c]
    float*          algl   = (float*)alloc(512UL * 768 * 4);              // local weights
    float*          outg   = (float*)alloc(512UL * 768 * 4);              // out_g fp32
    unsigned short* simbar = (unsigned short*)alloc(12UL * 512 * 768 * 2);// simbar bf16
    unsigned short* attnb  = (unsigned short*)alloc(512UL * 768 * 2);     // attn out bf16
    float*          bias1  = (float*)alloc(2304UL * 4);                   // [bq|bkv]
    float*          zbuf   = (float*)alloc(768UL * 4);                    // zeros

    // prep
    cast_bf16_kernel<<<384, 256, 0, stream>>>(x, xb, 512L * 768 / 4);
    cast_bf16_kernel<<<1152, 256, 0, stream>>>(Wkv, wkvb, 768L * 1536 / 4);
    transpose_cast_kernel<<<dim3(12, 12), dim3(64, 16), 0, stream>>>(Wq, 768, w1t, 768);
    transpose_cast_kernel<<<dim3(24, 12), dim3(64, 16), 0, stream>>>(Wkv, 1536, w1t + 768L * 768, 768);
    transpose_cast_kernel<<<dim3(12, 12), dim3(64, 16), 0, stream>>>(Wp, 768, wpt, 768);
    bias_init_kernel<<<12, 256, 0, stream>>>(bq, bkv, bias1, zbuf);

    // GEMM1: qkv = x @ [Wq|Wkv] + bias (512x2304, K=768); q->qkv+qb, k_x->kT, v_x->qkv
    gemm_bf16_kernel<2, 2, 2, 1><<<dim3(36, 8), 256, 0, stream>>>(
        xb, 768, w1t, 768, bias1, qkv, 2304, 768, kTbuf, qb, nullptr, 0, 0, 0, 0);

    // qW GEMM: per head h: qW_h = q_h (512x64) @ Wk_h^T -> (512x768) bf16, K=64
    gemm_bf16_kernel<2, 2, 2, 2><<<dim3(12, 8, 12), 256, 0, stream>>>(
        qb, 768, wkvb, 1536, zbuf, qWb, 768, 64, nullptr, nullptr, nullptr,
        64, 64, 512L * 768, 0);

    // B1: scores + softmax + out_g
    attn_b1_kernel<<<dim3(256, 2), 768, 0, stream>>>(sim, qkv, kTbuf, qWb, bkv, outg, algl);

    // B2: simbar = al @ sim
    attn_b2_kernel<<<dim3(256, 2), 256, 0, stream>>>(sim, algl, simbar);

    // out_l GEMM: per head: attnb = f2bf(simbar_h @ Wv_h + outg) (accumulate)
    gemm_bf16_kernel<2, 2, 2, 2><<<dim3(1, 8, 12), 256, 0, stream>>>(
        simbar, 768, w1t + 1536L * 768, 768, zbuf, attnb, 768, 768, nullptr, nullptr,
        outg, 512L * 768, 64L * 768, 0, 64);

    // GEMM3: out = attnb @ Wp + bp
    gemm_bf16_kernel<2, 2, 2, 0><<<dim3(12, 8), 256, 0, stream>>>(
        attnb, 768, wpt, 768, bp, out, 768, 768, nullptr, nullptr, nullptr, 0, 0, 0, 0);
}

// Round 6
// 261.716 us; speedup vs baseline: 1.8047x; 1.1794x over previous
//
#include <hip/hip_runtime.h>
#include <stdint.h>

#define DEV_INLINE __device__ __forceinline__

typedef __bf16 bf16x8 __attribute__((ext_vector_type(8)));
typedef float f32x4 __attribute__((ext_vector_type(4)));

typedef const __attribute__((address_space(1))) void* gas_ptr;
typedef __attribute__((address_space(3))) void* las_ptr;

DEV_INLINE unsigned short f2bf(float f) {
    union { float f; unsigned u; } v; v.f = f;
    unsigned r = v.u + 0x7fffu + ((v.u >> 16) & 1u);   // RNE
    return (unsigned short)(r >> 16);
}
DEV_INLINE float bf2f(unsigned short u) {
    union { unsigned u; float f; } v; v.u = ((unsigned)u) << 16;
    return v.f;
}

// ---------------- casts ----------------

__global__ void cast_bf16_kernel(const float* __restrict__ src,
                                 unsigned short* __restrict__ dst, long n4) {
    long i = (long)blockIdx.x * blockDim.x + threadIdx.x;
    if (i >= n4) return;
    float4 a = ((const float4*)src)[i];
    ushort4 o;
    o.x = f2bf(a.x); o.y = f2bf(a.y); o.z = f2bf(a.z); o.w = f2bf(a.w);
    ((ushort4*)dst)[i] = o;
}

// src: R x C fp32 row-major. dst: C x R bf16 row-major (ld_dst). R,C mult of 64.
__global__ void transpose_cast_kernel(const float* __restrict__ src, int C,
                                      unsigned short* __restrict__ dst, int ld_dst) {
    __shared__ float t[64][65];
    int c0 = blockIdx.x * 64, r0 = blockIdx.y * 64;
    int tx = threadIdx.x, ty = threadIdx.y;   // 64 x 16
    #pragma unroll
    for (int i = 0; i < 64; i += 16)
        t[ty + i][tx] = src[(long)(r0 + ty + i) * C + c0 + tx];
    __syncthreads();
    #pragma unroll
    for (int i = 0; i < 64; i += 16)
        dst[(long)(c0 + ty + i) * ld_dst + r0 + tx] = f2bf(t[tx][ty + i]);
}

// bias1[0:2304] = [bq|bkv]; zerobuf[0:768] = 0
__global__ void bias_init_kernel(const float* __restrict__ bq,
                                 const float* __restrict__ bkv,
                                 float* __restrict__ bias1,
                                 float* __restrict__ zerobuf) {
    int i = blockIdx.x * 256 + threadIdx.x;
    if (i < 2304) bias1[i] = (i < 768) ? bq[i] : bkv[i - 768];
    else if (i < 3072) zerobuf[i - 2304] = 0.f;
}

// ---------------- unified bf16 MFMA GEMM ----------------
// A: M x K bf16 (lda). BT: N x K bf16 (ldb) == B^T. Both LDS-staged via
// global_load_lds w=16 with XOR chunk swizzle (0 bank conflicts, R1-proven).
// 64x64 tile <2,2,2>. Batch z: zb=z/12, zh=z%12; A += zb*aZb + zh*aZh,
// BT += zb*bZb + zh*bZh, out index = zb*oZb + zh*oZh + row*ldc + col.
// OUT: 0=f32, 1=bf16. CIN: add fp32 cin[idx]. G1E: GEMM1 special epilogue
// (q -> qf fp32 + qb bf16; k_x -> kxb bf16; v_x -> vxT bf16 transposed).

template <int WM, int WN, int WAVES_M, int OUT, bool CIN, bool G1E>
__global__ __launch_bounds__(256)
void gemm_bf16_kernel(const unsigned short* __restrict__ A, int lda,
                      const unsigned short* __restrict__ BT, int ldb,
                      const float* __restrict__ bias,
                      void* __restrict__ Cout, int ldc, int K,
                      const float* __restrict__ cin,
                      long aZb, long aZh, long bZb, long bZh, long oZb, long oZh,
                      float* __restrict__ g1_qf, unsigned short* __restrict__ g1_qb,
                      unsigned short* __restrict__ g1_kxb,
                      unsigned short* __restrict__ g1_vxT) {
    constexpr int TR = WAVES_M * WM * 16;
    constexpr int TC = (4 / WAVES_M) * WN * 16;
    __shared__ unsigned short As[TR * 64];
    __shared__ unsigned short Bs[TC * 64];
    const int tid = threadIdx.x;
    const int w = tid >> 6, lane = tid & 63;
    const int lm = lane & 15, quad = lane >> 4;
    const int z = blockIdx.z;
    const int zb = z / 12, zh = z % 12;
    A  += zb * aZb + zh * aZh;
    BT += zb * bZb + zh * bZh;
    const long obase = zb * oZb + zh * oZh;
    const long tm = (long)blockIdx.y * TR;
    const long tn = (long)blockIdx.x * TC;
    const int m_off = (w % WAVES_M) * WM * 16;
    const int n_off = (w / WAVES_M) * WN * 16;
    const int lrow8 = lane >> 3;
    const int lcol_sw = (((lane & 7) ^ lrow8) * 8);

    f32x4 acc[WM][WN];
    #pragma unroll
    for (int mi = 0; mi < WM; ++mi)
        #pragma unroll
        for (int ni = 0; ni < WN; ++ni) acc[mi][ni] = f32x4{0.f, 0.f, 0.f, 0.f};

    for (int k0 = 0; k0 < K; k0 += 64) {
        __syncthreads();
        #pragma unroll
        for (int i = 0; i < TR / 32; ++i) {
            int r0 = w * (TR / 4) + i * 8;
            const unsigned short* ga = A + (tm + r0 + lrow8) * lda + k0 + lcol_sw;
            __builtin_amdgcn_global_load_lds((gas_ptr)ga, (las_ptr)(As + r0 * 64), 16, 0, 0);
        }
        #pragma unroll
        for (int i = 0; i < TC / 32; ++i) {
            int r0 = w * (TC / 4) + i * 8;
            const unsigned short* gb = BT + (tn + r0 + lrow8) * ldb + k0 + lcol_sw;
            __builtin_amdgcn_global_load_lds((gas_ptr)gb, (las_ptr)(Bs + r0 * 64), 16, 0, 0);
        }
        __syncthreads();
        #pragma unroll
        for (int kk = 0; kk < 2; ++kk) {
            bf16x8 af[WM], bfr[WN];
            #pragma unroll
            for (int mi = 0; mi < WM; ++mi) {
                int r = m_off + mi * 16 + lm;
                af[mi] = *(const bf16x8*)(As + r * 64 + (((kk * 4 + quad) ^ (r & 7)) * 8));
            }
            #pragma unroll
            for (int ni = 0; ni < WN; ++ni) {
                int r = n_off + ni * 16 + lm;
                bfr[ni] = *(const bf16x8*)(Bs + r * 64 + (((kk * 4 + quad) ^ (r & 7)) * 8));
            }
            #pragma unroll
            for (int mi = 0; mi < WM; ++mi)
                #pragma unroll
                for (int ni = 0; ni < WN; ++ni)
                    acc[mi][ni] = __builtin_amdgcn_mfma_f32_16x16x32_bf16(
                        af[mi], bfr[ni], acc[mi][ni], 0, 0, 0);
        }
    }

    #pragma unroll
    for (int mi = 0; mi < WM; ++mi) {
        #pragma unroll
        for (int ni = 0; ni < WN; ++ni) {
            long col = tn + n_off + ni * 16 + lm;
            float bv = bias[col];
            #pragma unroll
            for (int r = 0; r < 4; ++r) {
                long row = tm + m_off + mi * 16 + quad * 4 + r;   // C/D: col=lane&15, row=quad*4+reg
                float v = acc[mi][ni][r] + bv;
                if (G1E) {
                    if (col < 768) {
                        g1_qf[row * 768 + col] = v;
                        g1_qb[row * 768 + col] = f2bf(v);
                    } else if (col < 1536) {
                        g1_kxb[row * 768 + (col - 768)] = f2bf(v);
                    } else {
                        int j = (int)col - 1536, h = j >> 6, d = j & 63;
                        int bb = (int)row >> 8, n = (int)row & 255;
                        g1_vxT[((long)(bb * 12 + h) * 64 + d) * 256 + n] = f2bf(v);
                    }
                } else {
                    long idx = obase + row * ldc + col;
                    if (CIN) v += cin[idx];
                    if (OUT == 0) ((float*)Cout)[idx] = v;
                    else ((unsigned short*)Cout)[idx] = f2bf(v);
                }
            }
        }
    }
}

// ---------------- B1: sl (MFMA) + softmax + weight outputs ----------------
// Block per n_ = b*256+n, 256 threads (4 waves).
// sl[64m x 16h] = simb_tile[64 x 768] @ qW_n^T  via MFMA (qW LDS-resident,
// sim chunks via global_load_lds). sg read precomputed from sgbuf.
// Outputs: agb bf16 (global weights, for OUT_G GEMM), algl fp32 (for B2),
// outg0 fp32 = alm * bkv_v (bias seed for OUT_G).
__global__ __launch_bounds__(256)
void attn_b1_kernel(const unsigned short* __restrict__ simb,
                    const unsigned short* __restrict__ qWb,
                    const float* __restrict__ qf,
                    const float* __restrict__ bkv,
                    const float* __restrict__ sgbuf,
                    unsigned short* __restrict__ agb,
                    float* __restrict__ algl,
                    float* __restrict__ outg0) {
    __shared__ unsigned short qw_s[16 * 784];   // row stride 784 shorts -> 2-way banks (free)
    __shared__ unsigned short As[64 * 64];      // sim k-chunk, XOR-swizzled
    __shared__ float q_l[768];
    __shared__ float slb_s[12];
    __shared__ float scl[12][68];               // sl scores [h][m]

    const int t = threadIdx.x;
    const int lane = t & 63, w = t >> 6;
    const int lm = lane & 15, quad = lane >> 4;
    const int n = blockIdx.x, b = blockIdx.y;
    const int n_ = b * 256 + n;

    // stage qW rows h=0..15 (h>=12 = junk, finite, unused)
    {
        const int h = t >> 4, c0 = t & 15;
        const unsigned short* src = qWb + ((long)h * 512 + n_) * 768;
        #pragma unroll
        for (int j = 0; j < 6; ++j) {
            int ch = c0 + 16 * j;
            *(bf16x8*)(qw_s + h * 784 + ch * 8) = *(const bf16x8*)(src + ch * 8);
        }
    }
    q_l[t] = qf[(long)n_ * 768 + t];
    q_l[t + 256] = qf[(long)n_ * 768 + t + 256];
    q_l[t + 512] = qf[(long)n_ * 768 + t + 512];
    __syncthreads();
    if (t < 12) {   // sl bias term: q[h] . bkv_k[h]
        float s = 0.f;
        #pragma unroll 8
        for (int d = 0; d < 64; ++d) s += q_l[t * 64 + d] * bkv[t * 64 + d];
        slb_s[t] = s;
    }

    // sl MFMA: wave w owns m-rows [16w, 16w+16)
    const int lrow8 = lane >> 3;
    const int lcol_sw = (((lane & 7) ^ lrow8) * 8);
    f32x4 acc = {};
    for (int k0 = 0; k0 < 768; k0 += 64) {
        __syncthreads();
        #pragma unroll
        for (int i = 0; i < 2; ++i) {
            int r0 = w * 16 + i * 8;
            const unsigned short* ga = simb + ((long)n_ * 64 + r0 + lrow8) * 768 + k0 + lcol_sw;
            __builtin_amdgcn_global_load_lds((gas_ptr)ga, (las_ptr)(As + r0 * 64), 16, 0, 0);
        }
        __syncthreads();
        #pragma unroll
        for (int kk = 0; kk < 2; ++kk) {
            int r = w * 16 + lm;
            bf16x8 af = *(const bf16x8*)(As + r * 64 + (((kk * 4 + quad) ^ (r & 7)) * 8));
            bf16x8 bf_ = *(const bf16x8*)(qw_s + lm * 784 + k0 + kk * 32 + quad * 8);
            acc = __builtin_amdgcn_mfma_f32_16x16x32_bf16(af, bf_, acc, 0, 0, 0);
        }
    }
    if (lm < 12) {
        #pragma unroll
        for (int r = 0; r < 4; ++r)
            scl[lm][w * 16 + quad * 4 + r] = (acc[r] + slb_s[lm]) * 0.125f;
    }
    __syncthreads();

    // softmax: wave w handles heads h = 3w..3w+2; 5 scores per lane
    #pragma unroll
    for (int i = 0; i < 3; ++i) {
        const int h = w * 3 + i;
        const float* sgr = sgbuf + (long)(b * 12 + h) * 65536 + (long)n * 256;
        float v0 = sgr[lane] * 0.125f, v1 = sgr[lane + 64] * 0.125f,
              v2 = sgr[lane + 128] * 0.125f, v3 = sgr[lane + 192] * 0.125f;
        float v4 = scl[h][lane];
        float mx = fmaxf(fmaxf(fmaxf(v0, v1), fmaxf(v2, v3)), v4);
        #pragma unroll
        for (int off = 32; off > 0; off >>= 1) mx = fmaxf(mx, __shfl_xor(mx, off));
        float e0 = __expf(v0 - mx), e1 = __expf(v1 - mx), e2 = __expf(v2 - mx),
              e3 = __expf(v3 - mx), e4 = __expf(v4 - mx);
        float s = e0 + e1 + e2 + e3 + e4;
        #pragma unroll
        for (int off = 32; off > 0; off >>= 1) s += __shfl_xor(s, off);
        float inv = __frcp_rn(s);
        unsigned short* agr = agb + (long)(b * 12 + h) * 65536 + (long)n * 256;
        agr[lane] = f2bf(e0 * inv); agr[lane + 64] = f2bf(e1 * inv);
        agr[lane + 128] = f2bf(e2 * inv); agr[lane + 192] = f2bf(e3 * inv);
        float al = e4 * inv;
        algl[(long)n_ * 768 + h * 64 + lane] = al;
        float am = al;
        #pragma unroll
        for (int off = 32; off > 0; off >>= 1) am += __shfl_xor(am, off);
        outg0[(long)n_ * 768 + h * 64 + lane] = am * bkv[768 + h * 64 + lane];
    }
}

// ---------------- B2: simbar[h][n'][c] = sum_m al[h][m] * simb[n',m,c] ----------------
__global__ __launch_bounds__(256)
void attn_b2_kernel(const unsigned short* __restrict__ simb,
                    const float* __restrict__ algl,
                    unsigned short* __restrict__ simbar) {
    __shared__ float al_l[768];
    const int t = threadIdx.x;
    const int n_ = blockIdx.y * 256 + blockIdx.x;
    al_l[t] = algl[(long)n_ * 768 + t];
    al_l[t + 256] = algl[(long)n_ * 768 + t + 256];
    al_l[t + 512] = algl[(long)n_ * 768 + t + 512];
    __syncthreads();

    float acc[12][3] = {};
    const unsigned short* sbase = simb + (long)n_ * 64 * 768;
    for (int m = 0; m < 64; ++m) {
        float s0 = bf2f(sbase[(long)m * 768 + t]);
        float s1 = bf2f(sbase[(long)m * 768 + t + 256]);
        float s2 = bf2f(sbase[(long)m * 768 + t + 512]);
        #pragma unroll
        for (int h = 0; h < 12; ++h) {
            float a = al_l[h * 64 + m];
            acc[h][0] += a * s0; acc[h][1] += a * s1; acc[h][2] += a * s2;
        }
    }
    #pragma unroll
    for (int h = 0; h < 12; ++h) {
        unsigned short* dst = simbar + ((long)h * 512 + n_) * 768;
        dst[t] = f2bf(acc[h][0]);
        dst[t + 256] = f2bf(acc[h][1]);
        dst[t + 512] = f2bf(acc[h][2]);
    }
}

// ---------------- launch ----------------

extern "C" void kernel_launch(void* const* d_in, const int* in_sizes, int n_in,
                              void* d_out, int out_size, void* d_ws, size_t ws_size,
                              hipStream_t stream) {
    const float* x   = (const float*)d_in[0];   // (2,256,768)
    const float* sim = (const float*)d_in[1];   // (2,256,64,768)
    const float* Wq  = (const float*)d_in[2];   // (768,768)
    const float* bq  = (const float*)d_in[3];   // (768)
    const float* Wkv = (const float*)d_in[4];   // (768,1536)
    const float* bkv = (const float*)d_in[5];   // (1536)
    const float* Wp  = (const float*)d_in[6];   // (768,768)
    const float* bp  = (const float*)d_in[7];   // (768)
    float* out = (float*)d_out;                 // (2,256,768) fp32

    char* ws = (char*)d_ws;
    size_t off = 0;
    auto alloc = [&](size_t bytes) {
        char* p = ws + off;
        off += (bytes + 255) & ~(size_t)255;
        return p;
    };
    unsigned short* simb   = (unsigned short*)alloc(32768UL * 768 * 2);     // sim bf16
    unsigned short* xb     = (unsigned short*)alloc(512UL * 768 * 2);       // x bf16
    unsigned short* w1t    = (unsigned short*)alloc(2304UL * 768 * 2);      // [Wq|Wkv]^T bf16
    unsigned short* wkvb   = (unsigned short*)alloc(768UL * 1536 * 2);      // Wkv bf16
    unsigned short* wpt    = (unsigned short*)alloc(768UL * 768 * 2);       // Wp^T bf16
    float*          qf     = (float*)alloc(512UL * 768 * 4);                // q fp32
    unsigned short* qb     = (unsigned short*)alloc(512UL * 768 * 2);       // q bf16
    unsigned short* kxb    = (unsigned short*)alloc(512UL * 768 * 2);       // k_x bf16
    unsigned short* vxT    = (unsigned short*)alloc(24UL * 64 * 256 * 2);   // v_x^T per (b,h)
    unsigned short* qWb    = (unsigned short*)alloc(16UL * 512 * 768 * 2);  // qW bf16 (16 heads, 12-15 junk)
    float*          sgbuf  = (float*)alloc(24UL * 65536 * 4);               // sg fp32 (b,h,n,k)
    unsigned short* agb    = (unsigned short*)alloc(24UL * 65536 * 2);      // ag bf16
    float*          algl   = (float*)alloc(512UL * 768 * 4);                // al fp32
    float*          outg0  = (float*)alloc(512UL * 768 * 4);                // alm*bkv_v fp32
    float*          outg   = (float*)alloc(512UL * 768 * 4);                // out_g fp32
    unsigned short* simbar = (unsigned short*)alloc(12UL * 512 * 768 * 2);  // simbar bf16
    unsigned short* attnb  = (unsigned short*)alloc(512UL * 768 * 2);       // attn out bf16
    float*          bias1  = (float*)alloc(2304UL * 4);                     // [bq|bkv]
    float*          zbuf   = (float*)alloc(768UL * 4);                      // zeros

    // prep
    cast_bf16_kernel<<<24576, 256, 0, stream>>>(sim, simb, 32768L * 768 / 4);
    cast_bf16_kernel<<<384, 256, 0, stream>>>(x, xb, 512L * 768 / 4);
    cast_bf16_kernel<<<1152, 256, 0, stream>>>(Wkv, wkvb, 768L * 1536 / 4);
    transpose_cast_kernel<<<dim3(12, 12), dim3(64, 16), 0, stream>>>(Wq, 768, w1t, 768);
    transpose_cast_kernel<<<dim3(24, 12), dim3(64, 16), 0, stream>>>(Wkv, 1536, w1t + 768L * 768, 768);
    transpose_cast_kernel<<<dim3(12, 12), dim3(64, 16), 0, stream>>>(Wp, 768, wpt, 768);
    bias_init_kernel<<<12, 256, 0, stream>>>(bq, bkv, bias1, zbuf);

    // GEMM1: x @ [Wq|Wkv] + bias -> qf/qb, kxb, vxT   (512 x 2304, K=768)
    gemm_bf16_kernel<2, 2, 2, 0, false, true><<<dim3(36, 8, 1), 256, 0, stream>>>(
        xb, 768, w1t, 768, bias1, nullptr, 768, 768, nullptr,
        0, 0, 0, 0, 0, 0, qf, qb, kxb, vxT);

    // qW GEMM: qW_h = q_h @ Wk_h^T  (z=h: 512x768, K=64) -> bf16
    gemm_bf16_kernel<2, 2, 2, 1, false, false><<<dim3(12, 8, 12), 256, 0, stream>>>(
        qb, 768, wkvb, 1536, zbuf, qWb, 768, 64, nullptr,
        0, 64, 0, 64, 0, 512L * 768, nullptr, nullptr, nullptr, nullptr);

    // SG GEMM: sg = q_h @ k_x,h^T per (b,h)  (z=b*12+h: 256x256, K=64) -> fp32
    gemm_bf16_kernel<2, 2, 2, 0, false, false><<<dim3(4, 4, 24), 256, 0, stream>>>(
        qb, 768, kxb, 768, zbuf, sgbuf, 256, 64, nullptr,
        196608, 64, 196608, 64, 786432, 65536, nullptr, nullptr, nullptr, nullptr);

    // B1: sl MFMA + softmax -> agb, algl, outg0
    attn_b1_kernel<<<dim3(256, 2), 256, 0, stream>>>(
        simb, qWb, qf, bkv, sgbuf, agb, algl, outg0);

    // B2: simbar = al @ simb -> bf16
    attn_b2_kernel<<<dim3(256, 2), 256, 0, stream>>>(simb, algl, simbar);

    // OUT_G GEMM: outg = ag @ v_x + outg0 per (b,h)  (256x64, K=256) -> fp32
    gemm_bf16_kernel<2, 2, 2, 0, true, false><<<dim3(1, 4, 24), 256, 0, stream>>>(
        agb, 256, vxT, 256, zbuf, outg, 768, 256, outg0,
        786432, 65536, 196608, 16384, 196608, 64, nullptr, nullptr, nullptr, nullptr);

    // out_l GEMM: attnb = bf16(simbar_h @ Wv_h + outg)  (z=h: 512x64, K=768)
    gemm_bf16_kernel<2, 2, 2, 1, true, false><<<dim3(1, 8, 12), 256, 0, stream>>>(
        simbar, 768, w1t + 1536L * 768, 768, zbuf, attnb, 768, 768, outg,
        0, 393216, 0, 49152, 0, 64, nullptr, nullptr, nullptr, nullptr);

    // GEMM3: out = attnb @ Wp + bp
    gemm_bf16_kernel<2, 2, 2, 0, false, false><<<dim3(12, 8, 1), 256, 0, stream>>>(
        attnb, 768, wpt, 768, bp, out, 768, 768, nullptr,
        0, 0, 0, 0, 0, 0, nullptr, nullptr, nullptr, nullptr);
}

// Round 7
// 253.403 us; speedup vs baseline: 1.8640x; 1.0328x over previous
//
#include <hip/hip_runtime.h>
#include <stdint.h>

#define DEV_INLINE __device__ __forceinline__

typedef __bf16 bf16x8 __attribute__((ext_vector_type(8)));
typedef float f32x4 __attribute__((ext_vector_type(4)));

typedef const __attribute__((address_space(1))) void* gas_ptr;
typedef __attribute__((address_space(3))) void* las_ptr;

DEV_INLINE unsigned short f2bf(float f) {
    union { float f; unsigned u; } v; v.f = f;
    unsigned r = v.u + 0x7fffu + ((v.u >> 16) & 1u);   // RNE
    return (unsigned short)(r >> 16);
}
DEV_INLINE float bf2f(unsigned short u) {
    union { unsigned u; float f; } v; v.u = ((unsigned)u) << 16;
    return v.f;
}

// ---------------- casts ----------------

__global__ void cast_bf16_kernel(const float* __restrict__ src,
                                 unsigned short* __restrict__ dst, long n4) {
    long i = (long)blockIdx.x * blockDim.x + threadIdx.x;
    if (i >= n4) return;
    float4 a = ((const float4*)src)[i];
    ushort4 o;
    o.x = f2bf(a.x); o.y = f2bf(a.y); o.z = f2bf(a.z); o.w = f2bf(a.w);
    ((ushort4*)dst)[i] = o;
}

// src: R x C fp32 row-major. dst: C x R bf16 row-major (ld_dst). R,C mult of 64.
__global__ void transpose_cast_kernel(const float* __restrict__ src, int C,
                                      unsigned short* __restrict__ dst, int ld_dst) {
    __shared__ float t[64][65];
    int c0 = blockIdx.x * 64, r0 = blockIdx.y * 64;
    int tx = threadIdx.x, ty = threadIdx.y;   // 64 x 16
    #pragma unroll
    for (int i = 0; i < 64; i += 16)
        t[ty + i][tx] = src[(long)(r0 + ty + i) * C + c0 + tx];
    __syncthreads();
    #pragma unroll
    for (int i = 0; i < 64; i += 16)
        dst[(long)(c0 + ty + i) * ld_dst + r0 + tx] = f2bf(t[tx][ty + i]);
}

// bias1[0:2304] = [bq|bkv]; zerobuf[0:768] = 0
__global__ void bias_init_kernel(const float* __restrict__ bq,
                                 const float* __restrict__ bkv,
                                 float* __restrict__ bias1,
                                 float* __restrict__ zerobuf) {
    int i = blockIdx.x * 256 + threadIdx.x;
    if (i < 2304) bias1[i] = (i < 768) ? bq[i] : bkv[i - 768];
    else if (i < 3072) zerobuf[i - 2304] = 0.f;
}

// ---------------- unified bf16 MFMA GEMM ----------------
// A: M x K bf16 (lda). BT: N x K bf16 (ldb) == B^T. Both LDS-staged via
// global_load_lds w=16 with XOR chunk swizzle (0 bank conflicts, R1-proven).
// 64x64 tile <2,2,2>. Batch z: zb=z/12, zh=z%12; A += zb*aZb + zh*aZh,
// BT += zb*bZb + zh*bZh, out index = zb*oZb + zh*oZh + row*ldc + col.
// OUT: 0=f32, 1=bf16. CIN: add fp32 cin[idx]. G1E: GEMM1 special epilogue
// (q -> qf fp32 + qb bf16; k_x -> kxb bf16; v_x -> vxT bf16 transposed).

template <int WM, int WN, int WAVES_M, int OUT, bool CIN, bool G1E>
__global__ __launch_bounds__(256)
void gemm_bf16_kernel(const unsigned short* __restrict__ A, int lda,
                      const unsigned short* __restrict__ BT, int ldb,
                      const float* __restrict__ bias,
                      void* __restrict__ Cout, int ldc, int K,
                      const float* __restrict__ cin,
                      long aZb, long aZh, long bZb, long bZh, long oZb, long oZh,
                      float* __restrict__ g1_qf, unsigned short* __restrict__ g1_qb,
                      unsigned short* __restrict__ g1_kxb,
                      unsigned short* __restrict__ g1_vxT) {
    constexpr int TR = WAVES_M * WM * 16;
    constexpr int TC = (4 / WAVES_M) * WN * 16;
    __shared__ unsigned short As[TR * 64];
    __shared__ unsigned short Bs[TC * 64];
    const int tid = threadIdx.x;
    const int w = tid >> 6, lane = tid & 63;
    const int lm = lane & 15, quad = lane >> 4;
    const int z = blockIdx.z;
    const int zb = z / 12, zh = z % 12;
    A  += zb * aZb + zh * aZh;
    BT += zb * bZb + zh * bZh;
    const long obase = zb * oZb + zh * oZh;
    const long tm = (long)blockIdx.y * TR;
    const long tn = (long)blockIdx.x * TC;
    const int m_off = (w % WAVES_M) * WM * 16;
    const int n_off = (w / WAVES_M) * WN * 16;
    const int lrow8 = lane >> 3;
    const int lcol_sw = (((lane & 7) ^ lrow8) * 8);

    f32x4 acc[WM][WN];
    #pragma unroll
    for (int mi = 0; mi < WM; ++mi)
        #pragma unroll
        for (int ni = 0; ni < WN; ++ni) acc[mi][ni] = f32x4{0.f, 0.f, 0.f, 0.f};

    for (int k0 = 0; k0 < K; k0 += 64) {
        __syncthreads();
        #pragma unroll
        for (int i = 0; i < TR / 32; ++i) {
            int r0 = w * (TR / 4) + i * 8;
            const unsigned short* ga = A + (tm + r0 + lrow8) * lda + k0 + lcol_sw;
            __builtin_amdgcn_global_load_lds((gas_ptr)ga, (las_ptr)(As + r0 * 64), 16, 0, 0);
        }
        #pragma unroll
        for (int i = 0; i < TC / 32; ++i) {
            int r0 = w * (TC / 4) + i * 8;
            const unsigned short* gb = BT + (tn + r0 + lrow8) * ldb + k0 + lcol_sw;
            __builtin_amdgcn_global_load_lds((gas_ptr)gb, (las_ptr)(Bs + r0 * 64), 16, 0, 0);
        }
        __syncthreads();
        #pragma unroll
        for (int kk = 0; kk < 2; ++kk) {
            bf16x8 af[WM], bfr[WN];
            #pragma unroll
            for (int mi = 0; mi < WM; ++mi) {
                int r = m_off + mi * 16 + lm;
                af[mi] = *(const bf16x8*)(As + r * 64 + (((kk * 4 + quad) ^ (r & 7)) * 8));
            }
            #pragma unroll
            for (int ni = 0; ni < WN; ++ni) {
                int r = n_off + ni * 16 + lm;
                bfr[ni] = *(const bf16x8*)(Bs + r * 64 + (((kk * 4 + quad) ^ (r & 7)) * 8));
            }
            #pragma unroll
            for (int mi = 0; mi < WM; ++mi)
                #pragma unroll
                for (int ni = 0; ni < WN; ++ni)
                    acc[mi][ni] = __builtin_amdgcn_mfma_f32_16x16x32_bf16(
                        af[mi], bfr[ni], acc[mi][ni], 0, 0, 0);
        }
    }

    #pragma unroll
    for (int mi = 0; mi < WM; ++mi) {
        #pragma unroll
        for (int ni = 0; ni < WN; ++ni) {
            long col = tn + n_off + ni * 16 + lm;
            float bv = bias[col];
            #pragma unroll
            for (int r = 0; r < 4; ++r) {
                long row = tm + m_off + mi * 16 + quad * 4 + r;   // C/D: col=lane&15, row=quad*4+reg
                float v = acc[mi][ni][r] + bv;
                if (G1E) {
                    if (col < 768) {
                        g1_qf[row * 768 + col] = v;
                        g1_qb[row * 768 + col] = f2bf(v);
                    } else if (col < 1536) {
                        g1_kxb[row * 768 + (col - 768)] = f2bf(v);
                    } else {
                        int j = (int)col - 1536, h = j >> 6, d = j & 63;
                        int bb = (int)row >> 8, n = (int)row & 255;
                        g1_vxT[((long)(bb * 12 + h) * 64 + d) * 256 + n] = f2bf(v);
                    }
                } else {
                    long idx = obase + row * ldc + col;
                    if (CIN) v += cin[idx];
                    if (OUT == 0) ((float*)Cout)[idx] = v;
                    else ((unsigned short*)Cout)[idx] = f2bf(v);
                }
            }
        }
    }
}

// ---------------- fused attention: sl MFMA + softmax + simbar ----------------
// Block per n_ = b*256+n, 256 threads (4 waves), ~42 KB LDS (3 blocks/CU cap).
// Pass 1: stream sim fp32 in 64-wide k-chunks, convert to bf16 in-register,
//   ds_write_b128 into XOR-swizzled tile, 2 MFMAs/chunk -> sl scores.
// Softmax over [sg(256, from sgbuf) | sl(64)] per head; ag -> agb bf16 (global,
//   feeds OUT_G GEMM), al kept in LDS, alm*bkv_v -> outg0.
// Pass 2: simbar[h][c] = sum_m al[h][m]*sim[m][c], re-reading sim fp32 (L3-hot).
__global__ __launch_bounds__(256)
void attn_fused_kernel(const float* __restrict__ sim,
                       const unsigned short* __restrict__ qWb,
                       const float* __restrict__ qf,
                       const float* __restrict__ bkv,
                       const float* __restrict__ sgbuf,
                       unsigned short* __restrict__ agb,
                       float* __restrict__ outg0,
                       unsigned short* __restrict__ simbar) {
    __shared__ unsigned short qw_s[16 * 784];   // 25088 B (heads 12-15 junk rows)
    __shared__ unsigned short sim_s[64 * 64];   // 8192 B, one k-chunk, XOR-swizzled
    __shared__ float q_l[768];
    __shared__ float slb_s[12];
    __shared__ float scl[12][68];
    __shared__ float al_s[12][64];

    const int t = threadIdx.x;
    const int lane = t & 63, w = t >> 6;
    const int lm = lane & 15, quad = lane >> 4;
    const int n = blockIdx.x, b = blockIdx.y;
    const int n_ = b * 256 + n;
    const float* simn = sim + (long)n_ * 49152;   // 64 x 768

    // stage qW rows (h = t>>4, 6 chunks each) and q
    {
        const int h = t >> 4, c0 = t & 15;
        const unsigned short* src = qWb + ((long)h * 512 + n_) * 768;
        #pragma unroll
        for (int j = 0; j < 6; ++j) {
            int ch = c0 + 16 * j;
            *(bf16x8*)(qw_s + h * 784 + ch * 8) = *(const bf16x8*)(src + ch * 8);
        }
    }
    q_l[t] = qf[(long)n_ * 768 + t];
    q_l[t + 256] = qf[(long)n_ * 768 + t + 256];
    q_l[t + 512] = qf[(long)n_ * 768 + t + 512];
    __syncthreads();
    if (t < 12) {   // sl bias term: q[h] . bkv_k[h]
        float s = 0.f;
        #pragma unroll 8
        for (int d = 0; d < 64; ++d) s += q_l[t * 64 + d] * bkv[t * 64 + d];
        slb_s[t] = s;
    }

    // Pass 1: sl MFMA; wave w owns m-rows [16w, 16w+16)
    f32x4 acc = {};
    for (int k0 = 0; k0 < 768; k0 += 64) {
        __syncthreads();   // previous chunk's reads done
        #pragma unroll
        for (int i = 0; i < 2; ++i) {
            int id = t + 256 * i;            // 512 jobs: (row, 16B-chunk)
            int r = id >> 3, q = id & 7;
            const float* gp = simn + r * 768 + k0 + q * 8;
            float4 a = *(const float4*)gp;
            float4 c = *(const float4*)(gp + 4);
            union { bf16x8 v; unsigned short u[8]; } pk;
            pk.u[0] = f2bf(a.x); pk.u[1] = f2bf(a.y);
            pk.u[2] = f2bf(a.z); pk.u[3] = f2bf(a.w);
            pk.u[4] = f2bf(c.x); pk.u[5] = f2bf(c.y);
            pk.u[6] = f2bf(c.z); pk.u[7] = f2bf(c.w);
            *(bf16x8*)(sim_s + r * 64 + ((q ^ (r & 7)) * 8)) = pk.v;
        }
        __syncthreads();
        #pragma unroll
        for (int kk = 0; kk < 2; ++kk) {
            int r = w * 16 + lm;
            bf16x8 af = *(const bf16x8*)(sim_s + r * 64 + (((kk * 4 + quad) ^ (r & 7)) * 8));
            bf16x8 bf_ = *(const bf16x8*)(qw_s + lm * 784 + k0 + kk * 32 + quad * 8);
            acc = __builtin_amdgcn_mfma_f32_16x16x32_bf16(af, bf_, acc, 0, 0, 0);
        }
    }
    if (lm < 12) {
        #pragma unroll
        for (int r = 0; r < 4; ++r)
            scl[lm][w * 16 + quad * 4 + r] = (acc[r] + slb_s[lm]) * 0.125f;
    }
    __syncthreads();

    // softmax: wave w handles heads h = 3w..3w+2; 5 scores per lane
    #pragma unroll
    for (int i = 0; i < 3; ++i) {
        const int h = w * 3 + i;
        const float* sgr = sgbuf + (long)(b * 12 + h) * 65536 + (long)n * 256;
        float v0 = sgr[lane] * 0.125f, v1 = sgr[lane + 64] * 0.125f,
              v2 = sgr[lane + 128] * 0.125f, v3 = sgr[lane + 192] * 0.125f;
        float v4 = scl[h][lane];
        float mx = fmaxf(fmaxf(fmaxf(v0, v1), fmaxf(v2, v3)), v4);
        #pragma unroll
        for (int off = 32; off > 0; off >>= 1) mx = fmaxf(mx, __shfl_xor(mx, off));
        float e0 = __expf(v0 - mx), e1 = __expf(v1 - mx), e2 = __expf(v2 - mx),
              e3 = __expf(v3 - mx), e4 = __expf(v4 - mx);
        float s = e0 + e1 + e2 + e3 + e4;
        #pragma unroll
        for (int off = 32; off > 0; off >>= 1) s += __shfl_xor(s, off);
        float inv = __frcp_rn(s);
        unsigned short* agr = agb + (long)(b * 12 + h) * 65536 + (long)n * 256;
        agr[lane] = f2bf(e0 * inv); agr[lane + 64] = f2bf(e1 * inv);
        agr[lane + 128] = f2bf(e2 * inv); agr[lane + 192] = f2bf(e3 * inv);
        float al = e4 * inv;
        al_s[h][lane] = al;
        float am = al;
        #pragma unroll
        for (int off = 32; off > 0; off >>= 1) am += __shfl_xor(am, off);
        outg0[(long)n_ * 768 + h * 64 + lane] = am * bkv[768 + h * 64 + lane];
    }
    __syncthreads();

    // Pass 2: simbar (sim fp32 re-read, L3-hot; cols {t, t+256, t+512})
    float a0[12], a1[12], a2[12];
    #pragma unroll
    for (int h = 0; h < 12; ++h) { a0[h] = 0.f; a1[h] = 0.f; a2[h] = 0.f; }
    for (int m = 0; m < 64; ++m) {
        float s0 = simn[(long)m * 768 + t];
        float s1 = simn[(long)m * 768 + t + 256];
        float s2 = simn[(long)m * 768 + t + 512];
        #pragma unroll
        for (int h = 0; h < 12; ++h) {
            float a = al_s[h][m];
            a0[h] += a * s0; a1[h] += a * s1; a2[h] += a * s2;
        }
    }
    #pragma unroll
    for (int h = 0; h < 12; ++h) {
        unsigned short* dst = simbar + ((long)h * 512 + n_) * 768;
        dst[t] = f2bf(a0[h]);
        dst[t + 256] = f2bf(a1[h]);
        dst[t + 512] = f2bf(a2[h]);
    }
}

// ---------------- launch ----------------

extern "C" void kernel_launch(void* const* d_in, const int* in_sizes, int n_in,
                              void* d_out, int out_size, void* d_ws, size_t ws_size,
                              hipStream_t stream) {
    const float* x   = (const float*)d_in[0];   // (2,256,768)
    const float* sim = (const float*)d_in[1];   // (2,256,64,768)
    const float* Wq  = (const float*)d_in[2];   // (768,768)
    const float* bq  = (const float*)d_in[3];   // (768)
    const float* Wkv = (const float*)d_in[4];   // (768,1536)
    const float* bkv = (const float*)d_in[5];   // (1536)
    const float* Wp  = (const float*)d_in[6];   // (768,768)
    const float* bp  = (const float*)d_in[7];   // (768)
    float* out = (float*)d_out;                 // (2,256,768) fp32

    char* ws = (char*)d_ws;
    size_t off = 0;
    auto alloc = [&](size_t bytes) {
        char* p = ws + off;
        off += (bytes + 255) & ~(size_t)255;
        return p;
    };
    unsigned short* xb     = (unsigned short*)alloc(512UL * 768 * 2);       // x bf16
    unsigned short* w1t    = (unsigned short*)alloc(2304UL * 768 * 2);      // [Wq|Wkv]^T bf16
    unsigned short* wkvb   = (unsigned short*)alloc(768UL * 1536 * 2);      // Wkv bf16
    unsigned short* wpt    = (unsigned short*)alloc(768UL * 768 * 2);       // Wp^T bf16
    float*          qf     = (float*)alloc(512UL * 768 * 4);                // q fp32
    unsigned short* qb     = (unsigned short*)alloc(512UL * 768 * 2);       // q bf16
    unsigned short* kxb    = (unsigned short*)alloc(512UL * 768 * 2);       // k_x bf16
    unsigned short* vxT    = (unsigned short*)alloc(24UL * 64 * 256 * 2);   // v_x^T per (b,h)
    unsigned short* qWb    = (unsigned short*)alloc(16UL * 512 * 768 * 2);  // qW bf16 (heads 12-15 junk)
    float*          sgbuf  = (float*)alloc(24UL * 65536 * 4);               // sg fp32 (b,h,n,k)
    unsigned short* agb    = (unsigned short*)alloc(24UL * 65536 * 2);      // ag bf16
    float*          outg0  = (float*)alloc(512UL * 768 * 4);                // alm*bkv_v fp32
    float*          outg   = (float*)alloc(512UL * 768 * 4);                // out_g fp32
    unsigned short* simbar = (unsigned short*)alloc(12UL * 512 * 768 * 2);  // simbar bf16
    unsigned short* attnb  = (unsigned short*)alloc(512UL * 768 * 2);       // attn out bf16
    float*          bias1  = (float*)alloc(2304UL * 4);                     // [bq|bkv]
    float*          zbuf   = (float*)alloc(768UL * 4);                      // zeros

    // prep
    cast_bf16_kernel<<<384, 256, 0, stream>>>(x, xb, 512L * 768 / 4);
    cast_bf16_kernel<<<1152, 256, 0, stream>>>(Wkv, wkvb, 768L * 1536 / 4);
    transpose_cast_kernel<<<dim3(12, 12), dim3(64, 16), 0, stream>>>(Wq, 768, w1t, 768);
    transpose_cast_kernel<<<dim3(24, 12), dim3(64, 16), 0, stream>>>(Wkv, 1536, w1t + 768L * 768, 768);
    transpose_cast_kernel<<<dim3(12, 12), dim3(64, 16), 0, stream>>>(Wp, 768, wpt, 768);
    bias_init_kernel<<<12, 256, 0, stream>>>(bq, bkv, bias1, zbuf);

    // GEMM1: x @ [Wq|Wkv] + bias -> qf/qb, kxb, vxT   (512 x 2304, K=768)
    gemm_bf16_kernel<2, 2, 2, 0, false, true><<<dim3(36, 8, 1), 256, 0, stream>>>(
        xb, 768, w1t, 768, bias1, nullptr, 768, 768, nullptr,
        0, 0, 0, 0, 0, 0, qf, qb, kxb, vxT);

    // qW GEMM: qW_h = q_h @ Wk_h^T  (z=h: 512x768, K=64) -> bf16
    gemm_bf16_kernel<2, 2, 2, 1, false, false><<<dim3(12, 8, 12), 256, 0, stream>>>(
        qb, 768, wkvb, 1536, zbuf, qWb, 768, 64, nullptr,
        0, 64, 0, 64, 0, 512L * 768, nullptr, nullptr, nullptr, nullptr);

    // SG GEMM: sg = q_h @ k_x,h^T per (b,h)  (z=b*12+h: 256x256, K=64) -> fp32
    gemm_bf16_kernel<2, 2, 2, 0, false, false><<<dim3(4, 4, 24), 256, 0, stream>>>(
        qb, 768, kxb, 768, zbuf, sgbuf, 256, 64, nullptr,
        196608, 64, 196608, 64, 786432, 65536, nullptr, nullptr, nullptr, nullptr);

    // fused attention: sl MFMA + softmax + simbar (sim fp32 streamed, no pre-cast)
    attn_fused_kernel<<<dim3(256, 2), 256, 0, stream>>>(
        sim, qWb, qf, bkv, sgbuf, agb, outg0, simbar);

    // OUT_G GEMM: outg = ag @ v_x + outg0 per (b,h)  (256x64, K=256) -> fp32
    gemm_bf16_kernel<2, 2, 2, 0, true, false><<<dim3(1, 4, 24), 256, 0, stream>>>(
        agb, 256, vxT, 256, zbuf, outg, 768, 256, outg0,
        786432, 65536, 196608, 16384, 196608, 64, nullptr, nullptr, nullptr, nullptr);

    // out_l GEMM: attnb = bf16(simbar_h @ Wv_h + outg)  (z=h: 512x64, K=768)
    gemm_bf16_kernel<2, 2, 2, 1, true, false><<<dim3(1, 8, 12), 256, 0, stream>>>(
        simbar, 768, w1t + 1536L * 768, 768, zbuf, attnb, 768, 768, outg,
        0, 393216, 0, 49152, 0, 64, nullptr, nullptr, nullptr, nullptr);

    // GEMM3: out = attnb @ Wp + bp
    gemm_bf16_kernel<2, 2, 2, 0, false, false><<<dim3(12, 8, 1), 256, 0, stream>>>(
        attnb, 768, wpt, 768, bp, out, 768, 768, nullptr,
        0, 0, 0, 0, 0, 0, nullptr, nullptr, nullptr, nullptr);
}